// Round 4
// baseline (344.424 us; speedup 1.0000x reference)
//
#include <hip/hip_runtime.h>

#define B_ 16
#define S_ 20
#define L_ 64
#define T_ 1280
#define H_ 768
#define NITEMS 50000
#define TEMP 0.05f
#define EPSN 1e-8f

#define MT 80          // rows per m-tile (block)
#define ROWPAD 776     // LDS row stride in elements (768 + 8): breaks bank aliasing
#define NKT 24         // K steps of 32

typedef __attribute__((ext_vector_type(8))) short short8;
typedef __attribute__((ext_vector_type(4))) short short4v;
typedef __attribute__((ext_vector_type(4))) float f32x4;
typedef __attribute__((ext_vector_type(4))) unsigned int u32x4;

// full RNE float->bf16 (used once per element in pool)
__device__ __forceinline__ unsigned short f2bf(float f) {
    unsigned int u = __float_as_uint(f);
    u = u + 0x7FFFu + ((u >> 16) & 1u);
    return (unsigned short)(u >> 16);
}

// pack two floats -> two bf16 (round-half-up: +0x8000 then take hi16), 3 VALU
__device__ __forceinline__ unsigned int pack_bf16(float f0, float f1) {
    const unsigned int u0 = __float_as_uint(f0) + 0x8000u;
    const unsigned int u1 = __float_as_uint(f1) + 0x8000u;
    // D.b0=f0.b2 D.b1=f0.b3 D.b2=f1.b2 D.b3=f1.b3  (src0 -> bytes 4..7, src1 -> 0..3)
    return __builtin_amdgcn_perm(u1, u0, 0x07060302u);
}

// ---------------------------------------------------------------------------
// Kernel 1: per-(b,s) nan-mean pool, normalize, fold 1/(pn*TEMP), write bf16.
// ---------------------------------------------------------------------------
__global__ __launch_bounds__(192) void pool_kernel(const float* __restrict__ hidden,
                                                   const int* __restrict__ pos,
                                                   unsigned short* __restrict__ A,
                                                   int* __restrict__ valid) {
    const int row = blockIdx.x;  // 0..319
    const int b = row / S_, s = row % S_;
    const int tid = threadIdx.x;  // owns 4 consecutive h-cols

    __shared__ float wgt[L_];
    __shared__ int cntS;
    __shared__ float red[3];

    const int* pbase = pos + b * T_ + s * L_;
    if (tid < L_) {
        const int match = (pbase[tid] == s + 1) ? 1 : 0;
        unsigned long long bal = __ballot(match);
        wgt[tid] = match ? 1.0f : 0.0f;
        if (tid == 0) cntS = (int)__popcll(bal);
    }
    __syncthreads();

    const int cnt = cntS;
    const float inv = 1.0f / (float)(cnt > 0 ? cnt : 1);
    const float* hbase = hidden + ((size_t)b * T_ + (size_t)s * L_) * H_ + tid * 4;

    float a0 = 0.f, a1 = 0.f, a2 = 0.f, a3 = 0.f;
#pragma unroll 8
    for (int t = 0; t < L_; ++t) {
        const float w = wgt[t];
        const float4 v = *reinterpret_cast<const float4*>(hbase + (size_t)t * H_);
        a0 += w * v.x; a1 += w * v.y; a2 += w * v.z; a3 += w * v.w;
    }
    a0 *= inv; a1 *= inv; a2 *= inv; a3 *= inv;

    float ss = a0 * a0 + a1 * a1 + a2 * a2 + a3 * a3;
#pragma unroll
    for (int off = 32; off; off >>= 1) ss += __shfl_xor(ss, off, 64);
    const int wave = tid >> 6, lane = tid & 63;
    if (lane == 0) red[wave] = ss;
    __syncthreads();
    const float tot = red[0] + red[1] + red[2];
    const float scale = 1.0f / (fmaxf(sqrtf(tot), EPSN) * TEMP);

    short4v w4;
    w4[0] = (short)f2bf(a0 * scale);
    w4[1] = (short)f2bf(a1 * scale);
    w4[2] = (short)f2bf(a2 * scale);
    w4[3] = (short)f2bf(a3 * scale);
    *reinterpret_cast<short4v*>(A + (size_t)row * H_ + tid * 4) = w4;
    if (tid == 0) valid[row] = (cnt > 0) ? 1 : 0;
}

// ---------------------------------------------------------------------------
// Kernel 2: barrier-free streaming GEMM.
// Grid (4 m-tiles  x fastest, 196 n-tiles). Block = 512 threads (8 waves).
// A m-tile (80x768 bf16) staged ONCE into padded LDS; single __syncthreads.
// Then each wave independently streams its 32 emb columns: fp32 global->reg,
// pack->bf16, MFMA vs LDS A-frags. No barriers in the K-loop -> per-wave
// vmcnt pipelining, no collective drain. en computed in-reg from the same
// loads. 4 m-copies of emb served by L3 (same-n blocks dispatch-adjacent).
// ---------------------------------------------------------------------------
__global__ __launch_bounds__(512, 2) void gemm_kernel(const float* __restrict__ emb,
                                                      const unsigned short* __restrict__ A,
                                                      const int* __restrict__ valid,
                                                      float* __restrict__ out) {
    const int mt = blockIdx.x;   // 0..3  (fastest-varying: same-n blocks adjacent)
    const int nt = blockIdx.y;   // 0..195
    const int tid = threadIdx.x;
    const int wave = tid >> 6, lane = tid & 63, quad = lane >> 4, lq = lane & 15;

    __shared__ alignas(16) short As[MT * ROWPAD];  // 124160 B
    __shared__ int sMask[4];

    if (tid < 4) {
        int m = 0;
        for (int s = 0; s < S_; ++s) m |= (valid[(mt * 4 + tid) * S_ + s] ? 1 : 0) << s;
        sMask[tid] = m;
    }

    // ---- stage A rows [80*mt, 80*mt+80) into padded LDS (one time) ----
    const unsigned short* Ab = A + (size_t)(mt * MT) * H_;
#pragma unroll
    for (int i = 0; i < 15; ++i) {
        const int c = i * 512 + tid;        // 0..7679 (15*512 == 80*96 exactly)
        const int r = c / 96, cc = c % 96;  // 96 chunks of 8 elems per row
        const u32x4 v = *reinterpret_cast<const u32x4*>(Ab + r * H_ + cc * 8);
        *reinterpret_cast<u32x4*>(reinterpret_cast<char*>(As) + r * (ROWPAD * 2) + cc * 16) = v;
    }
    __syncthreads();  // the ONLY barrier

    // ---- per-wave column pointers (clamped; clamped cols never stored) ----
    const int n0w = nt * 256 + wave * 32;
    int r0 = n0w + lq;        if (r0 > NITEMS - 1) r0 = NITEMS - 1;
    int r1 = n0w + 16 + lq;   if (r1 > NITEMS - 1) r1 = NITEMS - 1;
    const float* bp0 = emb + (size_t)r0 * H_ + quad * 8;
    const float* bp1 = emb + (size_t)r1 * H_ + quad * 8;

    // A-frag LDS bases per mf (row mf*16+lq, col quad*8)
    const short* aBase[5];
#pragma unroll
    for (int mf = 0; mf < 5; ++mf)
        aBase[mf] = &As[(mf * 16 + lq) * ROWPAD + quad * 8];

    float rowSq0 = 0.f, rowSq1 = 0.f;
    f32x4 acc[5][2];
#pragma unroll
    for (int i = 0; i < 5; ++i) {
        acc[i][0] = (f32x4)0.f;
        acc[i][1] = (f32x4)0.f;
    }

#pragma unroll 8
    for (int kt = 0; kt < NKT; ++kt) {
        const float4 x0 = *reinterpret_cast<const float4*>(bp0 + kt * 32);
        const float4 y0 = *reinterpret_cast<const float4*>(bp0 + kt * 32 + 4);
        const float4 x1 = *reinterpret_cast<const float4*>(bp1 + kt * 32);
        const float4 y1 = *reinterpret_cast<const float4*>(bp1 + kt * 32 + 4);

        rowSq0 += x0.x * x0.x + x0.y * x0.y + x0.z * x0.z + x0.w * x0.w
                + y0.x * y0.x + y0.y * y0.y + y0.z * y0.z + y0.w * y0.w;
        rowSq1 += x1.x * x1.x + x1.y * x1.y + x1.z * x1.z + x1.w * x1.w
                + y1.x * y1.x + y1.y * y1.y + y1.z * y1.z + y1.w * y1.w;

        union { short8 s; u32x4 u; } bF0, bF1;
        bF0.u[0] = pack_bf16(x0.x, x0.y); bF0.u[1] = pack_bf16(x0.z, x0.w);
        bF0.u[2] = pack_bf16(y0.x, y0.y); bF0.u[3] = pack_bf16(y0.z, y0.w);
        bF1.u[0] = pack_bf16(x1.x, x1.y); bF1.u[1] = pack_bf16(x1.z, x1.w);
        bF1.u[2] = pack_bf16(y1.x, y1.y); bF1.u[3] = pack_bf16(y1.z, y1.w);

#pragma unroll
        for (int mf = 0; mf < 5; ++mf) {
            const short8 aF = *reinterpret_cast<const short8*>(aBase[mf] + kt * 32);
            acc[mf][0] = __builtin_amdgcn_mfma_f32_16x16x32_bf16(aF, bF0.s, acc[mf][0], 0, 0, 0);
            acc[mf][1] = __builtin_amdgcn_mfma_f32_16x16x32_bf16(aF, bF1.s, acc[mf][1], 0, 0, 0);
        }
    }

    // ---- en: sum rowSq across the 4 quads (each holds a disjoint k-slice) ----
    rowSq0 += __shfl_xor(rowSq0, 16, 64);
    rowSq0 += __shfl_xor(rowSq0, 32, 64);
    rowSq1 += __shfl_xor(rowSq1, 16, 64);
    rowSq1 += __shfl_xor(rowSq1, 32, 64);
    float invEn[2];
    invEn[0] = 1.0f / fmaxf(sqrtf(rowSq0), EPSN);
    invEn[1] = 1.0f / fmaxf(sqrtf(rowSq1), EPSN);

    // ---- epilogue: per-session masked max, /en, store ----
#pragma unroll
    for (int nf = 0; nf < 2; ++nf) {
        const int n = n0w + nf * 16 + lq;
        const float inv_en = invEn[nf];
#pragma unroll
        for (int bb = 0; bb < 4; ++bb) {
            const int rLo = bb * S_;
            const int msk = sMask[bb];
            const int mfLo = rLo >> 4;
            const int mfHi = (rLo + S_ - 1) >> 4;
            float lm = -__builtin_inff();
#pragma unroll
            for (int mf = mfLo; mf <= mfHi; ++mf)
#pragma unroll
                for (int e = 0; e < 4; ++e) {
                    const int r = mf * 16 + quad * 4 + e;  // C/D: row=quad*4+e
                    const unsigned off = (unsigned)(r - rLo);
                    const bool ok = (off < (unsigned)S_) && ((msk >> off) & 1);
                    lm = ok ? fmaxf(lm, acc[mf][nf][e]) : lm;
                }
            lm = fmaxf(lm, __shfl_xor(lm, 16, 64));
            lm = fmaxf(lm, __shfl_xor(lm, 32, 64));
            if (quad == 0 && n < NITEMS)
                out[(size_t)(mt * 4 + bb) * NITEMS + n] = lm * inv_en;
        }
    }
}

extern "C" void kernel_launch(void* const* d_in, const int* in_sizes, int n_in,
                              void* d_out, int out_size, void* d_ws, size_t ws_size,
                              hipStream_t stream) {
    const float* hidden = (const float*)d_in[0];   // [16,1280,768] f32
    const float* emb    = (const float*)d_in[1];   // [50000,768] f32
    const int*   pos    = (const int*)d_in[3];     // [16,1280] i32
    float* out = (float*)d_out;                    // [16,50000] f32

    unsigned short* Abf = (unsigned short*)d_ws;               // 320*768 bf16
    int* valid = (int*)((char*)d_ws + (size_t)320 * 768 * 2);  // 320 ints

    pool_kernel<<<dim3(320), dim3(192), 0, stream>>>(hidden, pos, Abf, valid);
    gemm_kernel<<<dim3(4, 196), dim3(512), 0, stream>>>(emb, Abf, valid, out);
}